// Round 5
// baseline (1190.864 us; speedup 1.0000x reference)
//
#include <hip/hip_runtime.h>

typedef _Float16 half_t;
typedef __attribute__((ext_vector_type(8))) _Float16 half8;
typedef __attribute__((ext_vector_type(4))) float floatx4;

// ---------------------------------------------------------------------------
// Round 5: register-prefetch software pipeline in the K-loop.
//   it:  barrier -> issue loads(it+1) -> LDS<-regs(it) -> barrier -> MFMA(it)
// Loads for it+1 fly during MFMA(it). A[pix][k], k = j*IN + i (j-major):
//   j<8 : exp2(-(pn' - g'_j)^2)   j==8: silu(p)   j==9 (pad): 0
// XOR-swizzled LDS (verified conflict-free round 4). Split-K via atomicAdd,
// conv bias folded into BN.
// ---------------------------------------------------------------------------

#define RBF_SCALE 2.1019644f   // 1.75 * sqrt(log2(e))

// ---- patch gather + LayerNorm -> pn' (fp16, pre-scaled), silu (fp16) ----
template<int C, int H, int W>
__global__ __launch_bounds__(256)
void ln_prep(const float* __restrict__ x,
             const float* __restrict__ lnw, const float* __restrict__ lnb,
             half_t* __restrict__ pn, half_t* __restrict__ sp)
{
    const int HW = H * W, IN = C * 9;
    const int NL = (IN + 63) / 64;
    const int wv = threadIdx.x >> 6, lane = threadIdx.x & 63;
    const int pix = blockIdx.x * 4 + wv;
    const int b = pix / HW, hw = pix % HW, h = hw / W, w = hw % W;
    const float* xb = x + (long)b * C * HW;

    float v[NL];
    float s = 0.f, s2 = 0.f;
    #pragma unroll
    for (int t = 0; t < NL; ++t) {
        int i = t * 64 + lane;
        float val = 0.f;
        if (i < IN) {
            int ch = i / 9, r = i - ch * 9;
            int y = h + r / 3 - 1, xx = w + r % 3 - 1;
            if (y >= 0 && y < H && xx >= 0 && xx < W)
                val = xb[ch * HW + y * W + xx];
        }
        v[t] = val; s += val; s2 += val * val;
    }
    #pragma unroll
    for (int off = 32; off > 0; off >>= 1) {
        s  += __shfl_down(s,  off, 64);
        s2 += __shfl_down(s2, off, 64);
    }
    s = __shfl(s, 0, 64); s2 = __shfl(s2, 0, 64);
    float mean = s / IN;
    float istd = rsqrtf(s2 / IN - mean * mean + 1e-5f);

    #pragma unroll
    for (int t = 0; t < NL; ++t) {
        int i = t * 64 + lane;
        if (i < IN) {
            float val = v[t];
            float pnv = (val - mean) * istd * lnw[i] + lnb[i];
            pn[(long)pix * IN + i] = (half_t)(pnv * RBF_SCALE);
            sp[(long)pix * IN + i] = (half_t)(val / (1.f + __expf(-val)));
        }
    }
}

// ---- fp32 weights -> fp16 [OUT][KPAD], j-major k = j*IN + i ----
template<int IN, int OUT, int KPAD>
__global__ __launch_bounds__(256)
void conv_w(const float* __restrict__ Ws, const float* __restrict__ Wb,
            half_t* __restrict__ Wt)
{
    int idx = blockIdx.x * 256 + threadIdx.x;
    if (idx >= OUT * KPAD) return;
    int o = idx / KPAD, k = idx - o * KPAD;
    float v = 0.f;
    if (k < IN * 9) {
        int j = k / IN, i = k - j * IN;
        v = (j < 8) ? Ws[(long)o * IN * 8 + i * 8 + j] : Wb[(long)o * IN + i];
    }
    Wt[idx] = (half_t)v;
}

// ---- fused A-gen + MFMA GEMM with register-prefetch pipeline ----
template<int IN, int OUT, int HW, int NB, int SPLIT>
__global__ __launch_bounds__(256)
void kan_gemm(const half_t* __restrict__ pn, const half_t* __restrict__ sp,
              const half_t* __restrict__ Wt, float* __restrict__ out)
{
    const int K = IN * 9, KPAD = (K + 63) & ~63, KIT = KPAD / 64;

    __shared__ half_t As[64 * 64];
    __shared__ half_t Bs[NB * 64 * 64];

    const int tid = threadIdx.x;
    const int row = tid >> 2, q = tid & 3;
    const int pix = blockIdx.x * 64 + row;
    const half_t* pnrow = pn + (long)pix * IN;
    const half_t* sprow = sp + (long)pix * IN;
    const int yoff = blockIdx.y * NB * 64;
    const half_t* wbase = Wt + (long)(yoff + row) * KPAD + q * 16;

    const int wv = tid >> 6, lane = tid & 63;
    const int lr = lane & 15, lq = lane >> 4;
    const int u0 = (2 * q) ^ (row & 7);         // swizzled 16B units
    const int u1 = (2 * q + 1) ^ (row & 7);

    floatx4 acc[NB][4] = {};

    const int it0 = (blockIdx.z * KIT) / SPLIT;
    const int it1 = ((blockIdx.z + 1) * KIT) / SPLIT;

    uint4 breg[2 * NB]; half8 p0, p1; int jc;

    // issue loads for iteration `it` into registers (no waits here)
    auto issue = [&](int it, uint4* br, half8& q0, half8& q1) -> int {
        const int k0 = it * 64;
        #pragma unroll
        for (int nb = 0; nb < NB; ++nb) {
            const uint4* src = (const uint4*)(wbase + (long)nb * 64 * KPAD + k0);
            br[2 * nb]     = src[0];
            br[2 * nb + 1] = src[1];
        }
        int cs = k0 + q * 16;
        int j = cs / IN;
        int i0 = cs - j * IN;
        if (j < 8) {
            q0 = *(const half8*)(pnrow + i0);
            q1 = *(const half8*)(pnrow + i0 + 8);
        } else if (j == 8) {
            q0 = *(const half8*)(sprow + i0);
            q1 = *(const half8*)(sprow + i0 + 8);
        } else {
            q0 = half8{}; q1 = half8{};
        }
        return j;
    };

    jc = issue(it0, breg, p0, p1);

    for (int it = it0; it < it1; ++it) {
        __syncthreads();   // previous MFMA reads done

        // ---- issue next iteration's loads (fly during store+MFMA below) ----
        uint4 bnx[2 * NB]; half8 n0, n1; int jn;
        if (it + 1 < it1) {
            jn = issue(it + 1, bnx, n0, n1);
        } else {
            jn = jc;
            #pragma unroll
            for (int t = 0; t < 2 * NB; ++t) bnx[t] = breg[t];
            n0 = p0; n1 = p1;
        }

        // ---- store current B tiles ----
        #pragma unroll
        for (int nb = 0; nb < NB; ++nb) {
            int r2 = nb * 64 + row;
            *(uint4*)&Bs[r2 * 64 + u0 * 8] = breg[2 * nb];
            *(uint4*)&Bs[r2 * 64 + u1 * 8] = breg[2 * nb + 1];
        }

        // ---- transform + store current A ----
        {
            half8 a0, a1;
            if (jc < 8) {
                float gj = RBF_SCALE * (-2.f + jc * (4.f / 7.f));
                #pragma unroll
                for (int kk = 0; kk < 8; ++kk) {
                    float v0 = (float)p0[kk] - gj;
                    a0[kk] = (half_t)__builtin_amdgcn_exp2f(-(v0 * v0));
                    float v1 = (float)p1[kk] - gj;
                    a1[kk] = (half_t)__builtin_amdgcn_exp2f(-(v1 * v1));
                }
            } else {
                a0 = p0; a1 = p1;   // silu passthrough or zero padding
            }
            *(half8*)&As[row * 64 + u0 * 8] = a0;
            *(half8*)&As[row * 64 + u1 * 8] = a1;
        }
        __syncthreads();

        // ---- MFMA ----
        #pragma unroll
        for (int ks = 0; ks < 2; ++ks) {
            half8 af[4], bf[NB];
            #pragma unroll
            for (int mf = 0; mf < 4; ++mf) {
                int r = mf * 16 + lr;
                af[mf] = *(const half8*)&As[r * 64 + (((ks * 4 + lq) ^ (r & 7)) * 8)];
            }
            #pragma unroll
            for (int nb = 0; nb < NB; ++nb) {
                int r = wv * NB * 16 + nb * 16 + lr;
                bf[nb] = *(const half8*)&Bs[r * 64 + (((ks * 4 + lq) ^ (r & 7)) * 8)];
            }
            #pragma unroll
            for (int nb = 0; nb < NB; ++nb)
                #pragma unroll
                for (int mf = 0; mf < 4; ++mf)
                    acc[nb][mf] = __builtin_amdgcn_mfma_f32_16x16x32_f16(
                        bf[nb], af[mf], acc[nb][mf], 0, 0, 0);
        }

        // ---- rotate pipeline registers ----
        #pragma unroll
        for (int t = 0; t < 2 * NB; ++t) breg[t] = bnx[t];
        p0 = n0; p1 = n1; jc = jn;
    }

    // ---- epilogue: rows = outputs (lq*4+reg), cols = pixels (lr) ----
    #pragma unroll
    for (int nb = 0; nb < NB; ++nb)
    #pragma unroll
    for (int mf = 0; mf < 4; ++mf)
    #pragma unroll
    for (int reg = 0; reg < 4; ++reg) {
        int o  = yoff + wv * NB * 16 + nb * 16 + lq * 4 + reg;
        int p2 = blockIdx.x * 64 + mf * 16 + lr;
        int b2 = p2 / HW, hw2 = p2 % HW;
        long off = ((long)b2 * OUT + o) * HW + hw2;
        if (SPLIT == 1) out[off] = acc[nb][mf][reg];
        else            atomicAdd(&out[off], acc[nb][mf][reg]);
    }
}

// ---- BatchNorm batch-stats (conv bias folded in) ----
__launch_bounds__(256)
__global__ void bn_stats(const float* __restrict__ h, const float* __restrict__ bias,
                         int C, int HW, int B, float* __restrict__ sums)
{
    int c = blockIdx.y;
    float bbc = bias[c];
    int total = B * HW;
    float s = 0.f, s2 = 0.f;
    for (int idx = blockIdx.x * 256 + threadIdx.x; idx < total; idx += 256 * gridDim.x) {
        int b = idx / HW, r = idx % HW;
        float v = h[((long)b * C + c) * HW + r] + bbc;
        s += v; s2 += v * v;
    }
    for (int off = 32; off > 0; off >>= 1) {
        s  += __shfl_down(s,  off, 64);
        s2 += __shfl_down(s2, off, 64);
    }
    __shared__ float rs[4], rs2[4];
    int lane = threadIdx.x & 63, wid = threadIdx.x >> 6;
    if (lane == 0) { rs[wid] = s; rs2[wid] = s2; }
    __syncthreads();
    if (threadIdx.x == 0) {
        atomicAdd(&sums[c],     rs[0] + rs[1] + rs[2] + rs[3]);
        atomicAdd(&sums[C + c], rs2[0] + rs2[1] + rs2[2] + rs2[3]);
    }
}

__launch_bounds__(256)
__global__ void bn_relu_pool(const float* __restrict__ h, const float* __restrict__ sums,
                             const float* __restrict__ bias,
                             const float* __restrict__ gamma, const float* __restrict__ beta,
                             float* __restrict__ out, int B, int C, int H, int W)
{
    int Ho = H / 2, Wo = W / 2;
    long total = (long)B * C * Ho * Wo;
    long idx = (long)blockIdx.x * 256 + threadIdx.x;
    if (idx >= total) return;
    int pw = idx % Wo; long t = idx / Wo;
    int ph = t % Ho; t /= Ho;
    int c = t % C; int b = (int)(t / C);

    float M = (float)B * H * W;
    float mean = sums[c] / M;
    float var  = sums[C + c] / M - mean * mean;
    float scale = gamma[c] * rsqrtf(var + 1e-5f);
    float shift = beta[c] - mean * scale + bias[c] * scale;  // fold conv bias

    const float* hp = h + ((long)b * C + c) * H * W;
    float m = 0.f;  // post-relu >= 0
    #pragma unroll
    for (int i = 0; i < 2; ++i)
        #pragma unroll
        for (int j = 0; j < 2; ++j) {
            float v = hp[(2 * ph + i) * W + 2 * pw + j] * scale + shift;
            m = fmaxf(m, v);
        }
    out[idx] = m;
}

extern "C" void kernel_launch(void* const* d_in, const int* in_sizes, int n_in,
                              void* d_out, int out_size, void* d_ws, size_t ws_size,
                              hipStream_t stream) {
    const float* x     = (const float*)d_in[0];
    const float* ln_w1 = (const float*)d_in[1];  const float* ln_b1 = (const float*)d_in[2];
    const float* Wb1   = (const float*)d_in[3];  const float* bb1   = (const float*)d_in[4];
    const float* Ws1   = (const float*)d_in[5];  const float* g1    = (const float*)d_in[6];
    const float* be1   = (const float*)d_in[7];
    const float* ln_w2 = (const float*)d_in[8];  const float* ln_b2 = (const float*)d_in[9];
    const float* Wb2   = (const float*)d_in[10]; const float* bb2   = (const float*)d_in[11];
    const float* Ws2   = (const float*)d_in[12]; const float* g2    = (const float*)d_in[13];
    const float* be2   = (const float*)d_in[14];
    const float* ln_w3 = (const float*)d_in[15]; const float* ln_b3 = (const float*)d_in[16];
    const float* Wb3   = (const float*)d_in[17]; const float* bb3   = (const float*)d_in[18];
    const float* Ws3   = (const float*)d_in[19]; const float* g3    = (const float*)d_in[20];
    const float* be3   = (const float*)d_in[21];

    const int B = 32;
    char* ws = (char*)d_ws;
    float*  convbuf = (float*)(ws + 0);              // 33,554,432
    float*  poolbuf = (float*)(ws + 33554432);       //  8,388,608
    float*  stats1  = (float*)(ws + 41943040);       //  2048 x3
    float*  stats2  = (float*)(ws + 41945088);
    float*  stats3  = (float*)(ws + 41947136);
    half_t* wt1     = (half_t*)(ws + 41949184);      //   172,032  (64 x 1344)
    half_t* wt2     = (half_t*)(ws + 42121216);      // 1,327,104  (128 x 5184)
    half_t* wt3     = (half_t*)(ws + 43448320);      // 5,308,416  (256 x 10368)
    half_t* pnbuf   = (half_t*)(ws + 48756736);      // 37,748,736 (max 131072x144)
    half_t* spbuf   = (half_t*)(ws + 86505472);      // 37,748,736
    // total: 124,254,208 B

    hipMemsetAsync(stats1, 0, 6144, stream);

    conv_w<144, 64, 1344><<<(64 * 1344 + 255) / 256, 256, 0, stream>>>(Ws1, Wb1, wt1);
    conv_w<576, 128, 5184><<<(128 * 5184 + 255) / 256, 256, 0, stream>>>(Ws2, Wb2, wt2);
    conv_w<1152, 256, 10368><<<(256 * 10368 + 255) / 256, 256, 0, stream>>>(Ws3, Wb3, wt3);

    // ---------------- layer 1: C=16, H=W=64, OUT=64, NB=1, SPLIT=1 ----------
    {
        const int H = 64, W = 64, OUT = 64;
        int npix = B * H * W;                    // 131072
        ln_prep<16, H, W><<<npix / 4, 256, 0, stream>>>(x, ln_w1, ln_b1, pnbuf, spbuf);
        kan_gemm<144, OUT, H * W, 1, 1><<<dim3(npix / 64, 1, 1), 256, 0, stream>>>(
            pnbuf, spbuf, wt1, convbuf);
        bn_stats<<<dim3(64, OUT), 256, 0, stream>>>(convbuf, bb1, OUT, H * W, B, stats1);
        long tot = (long)B * OUT * (H / 2) * (W / 2);
        bn_relu_pool<<<(tot + 255) / 256, 256, 0, stream>>>(
            convbuf, stats1, bb1, g1, be1, poolbuf, B, OUT, H, W);
    }
    // ---------------- layer 2: C=64, H=W=32, OUT=128, NB=2, SPLIT=4 ---------
    {
        const int H = 32, W = 32, OUT = 128;
        int npix = B * H * W;                    // 32768
        ln_prep<64, H, W><<<npix / 4, 256, 0, stream>>>(poolbuf, ln_w2, ln_b2, pnbuf, spbuf);
        hipMemsetAsync(convbuf, 0, (long)npix * OUT * 4, stream);   // 16.8 MB
        kan_gemm<576, OUT, H * W, 2, 4><<<dim3(npix / 64, 1, 4), 256, 0, stream>>>(
            pnbuf, spbuf, wt2, convbuf);
        bn_stats<<<dim3(16, OUT), 256, 0, stream>>>(convbuf, bb2, OUT, H * W, B, stats2);
        long tot = (long)B * OUT * (H / 2) * (W / 2);
        bn_relu_pool<<<(tot + 255) / 256, 256, 0, stream>>>(
            convbuf, stats2, bb2, g2, be2, poolbuf, B, OUT, H, W);
    }
    // ---------------- layer 3: C=128, H=W=16, OUT=256, NB=2 (y=2), SPLIT=4 --
    {
        const int H = 16, W = 16, OUT = 256;
        int npix = B * H * W;                    // 8192
        ln_prep<128, H, W><<<npix / 4, 256, 0, stream>>>(poolbuf, ln_w3, ln_b3, pnbuf, spbuf);
        hipMemsetAsync(convbuf, 0, (long)npix * OUT * 4, stream);   // 8.4 MB
        kan_gemm<1152, OUT, H * W, 2, 4><<<dim3(npix / 64, 2, 4), 256, 0, stream>>>(
            pnbuf, spbuf, wt3, convbuf);
        bn_stats<<<dim3(8, OUT), 256, 0, stream>>>(convbuf, bb3, OUT, H * W, B, stats3);
        long tot = (long)B * OUT * (H / 2) * (W / 2);  // 524288 == out_size
        bn_relu_pool<<<(tot + 255) / 256, 256, 0, stream>>>(
            convbuf, stats3, bb3, g3, be3, (float*)d_out, B, OUT, H, W);
    }
}

// Round 6
// 1171.562 us; speedup vs baseline: 1.0165x; 1.0165x over previous
//
#include <hip/hip_runtime.h>

typedef _Float16 half_t;
typedef __attribute__((ext_vector_type(8))) _Float16 half8;
typedef __attribute__((ext_vector_type(4))) float floatx4;

// ---------------------------------------------------------------------------
// Round 6: register-prefetch K-loop pipeline + ATOMIC-FREE split-K.
// Each (x,y,z) block stores its partial tile to partial[z] (plain coalesced
// stores); bn_stats / bn_relu_pool sum the SPLIT partials while streaming.
// A[pix][k], k = j*IN + i (j-major): j<8: exp2(-(pn'-g'_j)^2), j==8: silu(p).
// XOR-swizzled LDS (conflict-free, verified round 4). Conv bias folded in BN.
// ---------------------------------------------------------------------------

#define RBF_SCALE 2.1019644f   // 1.75 * sqrt(log2(e))

// ---- patch gather + LayerNorm -> pn' (fp16, pre-scaled), silu (fp16) ----
template<int C, int H, int W>
__global__ __launch_bounds__(256)
void ln_prep(const float* __restrict__ x,
             const float* __restrict__ lnw, const float* __restrict__ lnb,
             half_t* __restrict__ pn, half_t* __restrict__ sp)
{
    const int HW = H * W, IN = C * 9;
    const int NL = (IN + 63) / 64;
    const int wv = threadIdx.x >> 6, lane = threadIdx.x & 63;
    const int pix = blockIdx.x * 4 + wv;
    const int b = pix / HW, hw = pix % HW, h = hw / W, w = hw % W;
    const float* xb = x + (long)b * C * HW;

    float v[NL];
    float s = 0.f, s2 = 0.f;
    #pragma unroll
    for (int t = 0; t < NL; ++t) {
        int i = t * 64 + lane;
        float val = 0.f;
        if (i < IN) {
            int ch = i / 9, r = i - ch * 9;
            int y = h + r / 3 - 1, xx = w + r % 3 - 1;
            if (y >= 0 && y < H && xx >= 0 && xx < W)
                val = xb[ch * HW + y * W + xx];
        }
        v[t] = val; s += val; s2 += val * val;
    }
    #pragma unroll
    for (int off = 32; off > 0; off >>= 1) {
        s  += __shfl_down(s,  off, 64);
        s2 += __shfl_down(s2, off, 64);
    }
    s = __shfl(s, 0, 64); s2 = __shfl(s2, 0, 64);
    float mean = s / IN;
    float istd = rsqrtf(s2 / IN - mean * mean + 1e-5f);

    #pragma unroll
    for (int t = 0; t < NL; ++t) {
        int i = t * 64 + lane;
        if (i < IN) {
            float val = v[t];
            float pnv = (val - mean) * istd * lnw[i] + lnb[i];
            pn[(long)pix * IN + i] = (half_t)(pnv * RBF_SCALE);
            sp[(long)pix * IN + i] = (half_t)(val / (1.f + __expf(-val)));
        }
    }
}

// ---- fp32 weights -> fp16 [OUT][KPAD], j-major k = j*IN + i ----
template<int IN, int OUT, int KPAD>
__global__ __launch_bounds__(256)
void conv_w(const float* __restrict__ Ws, const float* __restrict__ Wb,
            half_t* __restrict__ Wt)
{
    int idx = blockIdx.x * 256 + threadIdx.x;
    if (idx >= OUT * KPAD) return;
    int o = idx / KPAD, k = idx - o * KPAD;
    float v = 0.f;
    if (k < IN * 9) {
        int j = k / IN, i = k - j * IN;
        v = (j < 8) ? Ws[(long)o * IN * 8 + i * 8 + j] : Wb[(long)o * IN + i];
    }
    Wt[idx] = (half_t)v;
}

// ---- fused A-gen + MFMA GEMM, register-prefetch pipeline, partial stores ----
template<int IN, int OUT, int HW, int NB, int SPLIT>
__global__ __launch_bounds__(256)
void kan_gemm(const half_t* __restrict__ pn, const half_t* __restrict__ sp,
              const half_t* __restrict__ Wt, float* __restrict__ out)
{
    const int K = IN * 9, KPAD = (K + 63) & ~63, KIT = KPAD / 64;
    const long PSTRIDE = (long)32 * HW * OUT;   // one partial buffer

    __shared__ half_t As[64 * 64];
    __shared__ half_t Bs[NB * 64 * 64];

    const int tid = threadIdx.x;
    const int row = tid >> 2, q = tid & 3;
    const int pix = blockIdx.x * 64 + row;
    const half_t* pnrow = pn + (long)pix * IN;
    const half_t* sprow = sp + (long)pix * IN;
    const int yoff = blockIdx.y * NB * 64;
    const half_t* wbase = Wt + (long)(yoff + row) * KPAD + q * 16;

    const int wv = tid >> 6, lane = tid & 63;
    const int lr = lane & 15, lq = lane >> 4;
    const int u0 = (2 * q) ^ (row & 7);         // swizzled 16B units
    const int u1 = (2 * q + 1) ^ (row & 7);

    floatx4 acc[NB][4] = {};

    const int it0 = (blockIdx.z * KIT) / SPLIT;
    const int it1 = ((blockIdx.z + 1) * KIT) / SPLIT;

    uint4 breg[2 * NB]; half8 p0, p1; int jc;

    // issue loads for iteration `it` into registers (no waits here)
    auto issue = [&](int it, uint4* br, half8& q0, half8& q1) -> int {
        const int k0 = it * 64;
        #pragma unroll
        for (int nb = 0; nb < NB; ++nb) {
            const uint4* src = (const uint4*)(wbase + (long)nb * 64 * KPAD + k0);
            br[2 * nb]     = src[0];
            br[2 * nb + 1] = src[1];
        }
        int cs = k0 + q * 16;
        int j = cs / IN;
        int i0 = cs - j * IN;
        if (j < 8) {
            q0 = *(const half8*)(pnrow + i0);
            q1 = *(const half8*)(pnrow + i0 + 8);
        } else if (j == 8) {
            q0 = *(const half8*)(sprow + i0);
            q1 = *(const half8*)(sprow + i0 + 8);
        } else {
            q0 = half8{}; q1 = half8{};
        }
        return j;
    };

    jc = issue(it0, breg, p0, p1);

    for (int it = it0; it < it1; ++it) {
        __syncthreads();   // previous MFMA reads done

        // ---- issue next iteration's loads (fly during store+MFMA below) ----
        uint4 bnx[2 * NB]; half8 n0, n1; int jn;
        if (it + 1 < it1) {
            jn = issue(it + 1, bnx, n0, n1);
        } else {
            jn = jc;
            #pragma unroll
            for (int t = 0; t < 2 * NB; ++t) bnx[t] = breg[t];
            n0 = p0; n1 = p1;
        }

        // ---- store current B tiles ----
        #pragma unroll
        for (int nb = 0; nb < NB; ++nb) {
            int r2 = nb * 64 + row;
            *(uint4*)&Bs[r2 * 64 + u0 * 8] = breg[2 * nb];
            *(uint4*)&Bs[r2 * 64 + u1 * 8] = breg[2 * nb + 1];
        }

        // ---- transform + store current A ----
        {
            half8 a0, a1;
            if (jc < 8) {
                float gj = RBF_SCALE * (-2.f + jc * (4.f / 7.f));
                #pragma unroll
                for (int kk = 0; kk < 8; ++kk) {
                    float v0 = (float)p0[kk] - gj;
                    a0[kk] = (half_t)__builtin_amdgcn_exp2f(-(v0 * v0));
                    float v1 = (float)p1[kk] - gj;
                    a1[kk] = (half_t)__builtin_amdgcn_exp2f(-(v1 * v1));
                }
            } else {
                a0 = p0; a1 = p1;   // silu passthrough or zero padding
            }
            *(half8*)&As[row * 64 + u0 * 8] = a0;
            *(half8*)&As[row * 64 + u1 * 8] = a1;
        }
        __syncthreads();

        // ---- MFMA ----
        #pragma unroll
        for (int ks = 0; ks < 2; ++ks) {
            half8 af[4], bf[NB];
            #pragma unroll
            for (int mf = 0; mf < 4; ++mf) {
                int r = mf * 16 + lr;
                af[mf] = *(const half8*)&As[r * 64 + (((ks * 4 + lq) ^ (r & 7)) * 8)];
            }
            #pragma unroll
            for (int nb = 0; nb < NB; ++nb) {
                int r = wv * NB * 16 + nb * 16 + lr;
                bf[nb] = *(const half8*)&Bs[r * 64 + (((ks * 4 + lq) ^ (r & 7)) * 8)];
            }
            #pragma unroll
            for (int nb = 0; nb < NB; ++nb)
                #pragma unroll
                for (int mf = 0; mf < 4; ++mf)
                    acc[nb][mf] = __builtin_amdgcn_mfma_f32_16x16x32_f16(
                        bf[nb], af[mf], acc[nb][mf], 0, 0, 0);
        }

        // ---- rotate pipeline registers ----
        #pragma unroll
        for (int t = 0; t < 2 * NB; ++t) breg[t] = bnx[t];
        p0 = n0; p1 = n1; jc = jn;
    }

    // ---- epilogue: plain stores into partial[z] ----
    float* pout = out + blockIdx.z * PSTRIDE;
    #pragma unroll
    for (int nb = 0; nb < NB; ++nb)
    #pragma unroll
    for (int mf = 0; mf < 4; ++mf)
    #pragma unroll
    for (int reg = 0; reg < 4; ++reg) {
        int o  = yoff + wv * NB * 16 + nb * 16 + lq * 4 + reg;
        int p2 = blockIdx.x * 64 + mf * 16 + lr;
        int b2 = p2 / HW, hw2 = p2 % HW;
        pout[((long)b2 * OUT + o) * HW + hw2] = acc[nb][mf][reg];
    }
}

// ---- BatchNorm batch-stats over SPLIT partials (conv bias folded in) ----
template<int SPLIT>
__launch_bounds__(256)
__global__ void bn_stats(const float* __restrict__ h, const float* __restrict__ bias,
                         int C, int HW, int B, float* __restrict__ sums)
{
    int c = blockIdx.y;
    float bbc = bias[c];
    int total = B * HW;
    long pstride = (long)total * C;
    float s = 0.f, s2 = 0.f;
    for (int idx = blockIdx.x * 256 + threadIdx.x; idx < total; idx += 256 * gridDim.x) {
        int b = idx / HW, r = idx % HW;
        long off = ((long)b * C + c) * HW + r;
        float v = bbc;
        #pragma unroll
        for (int sp = 0; sp < SPLIT; ++sp) v += h[sp * pstride + off];
        s += v; s2 += v * v;
    }
    for (int off = 32; off > 0; off >>= 1) {
        s  += __shfl_down(s,  off, 64);
        s2 += __shfl_down(s2, off, 64);
    }
    __shared__ float rs[4], rs2[4];
    int lane = threadIdx.x & 63, wid = threadIdx.x >> 6;
    if (lane == 0) { rs[wid] = s; rs2[wid] = s2; }
    __syncthreads();
    if (threadIdx.x == 0) {
        atomicAdd(&sums[c],     rs[0] + rs[1] + rs[2] + rs[3]);
        atomicAdd(&sums[C + c], rs2[0] + rs2[1] + rs2[2] + rs2[3]);
    }
}

template<int SPLIT>
__launch_bounds__(256)
__global__ void bn_relu_pool(const float* __restrict__ h, const float* __restrict__ sums,
                             const float* __restrict__ bias,
                             const float* __restrict__ gamma, const float* __restrict__ beta,
                             float* __restrict__ out, int B, int C, int H, int W)
{
    int Ho = H / 2, Wo = W / 2;
    long total = (long)B * C * Ho * Wo;
    long idx = (long)blockIdx.x * 256 + threadIdx.x;
    if (idx >= total) return;
    int pw = idx % Wo; long t = idx / Wo;
    int ph = t % Ho; t /= Ho;
    int c = t % C; int b = (int)(t / C);

    float M = (float)B * H * W;
    float mean = sums[c] / M;
    float var  = sums[C + c] / M - mean * mean;
    float scale = gamma[c] * rsqrtf(var + 1e-5f);
    float shift = beta[c] - mean * scale + bias[c] * scale;  // fold conv bias

    long pstride = (long)B * C * H * W;
    const float* hp = h + ((long)b * C + c) * H * W;
    float m = 0.f;  // post-relu >= 0
    #pragma unroll
    for (int i = 0; i < 2; ++i)
        #pragma unroll
        for (int j = 0; j < 2; ++j) {
            long off = (2 * ph + i) * W + 2 * pw + j;
            float v = 0.f;
            #pragma unroll
            for (int sp = 0; sp < SPLIT; ++sp) v += hp[sp * pstride + off];
            v = v * scale + shift;
            m = fmaxf(m, v);
        }
    out[idx] = m;
}

extern "C" void kernel_launch(void* const* d_in, const int* in_sizes, int n_in,
                              void* d_out, int out_size, void* d_ws, size_t ws_size,
                              hipStream_t stream) {
    const float* x     = (const float*)d_in[0];
    const float* ln_w1 = (const float*)d_in[1];  const float* ln_b1 = (const float*)d_in[2];
    const float* Wb1   = (const float*)d_in[3];  const float* bb1   = (const float*)d_in[4];
    const float* Ws1   = (const float*)d_in[5];  const float* g1    = (const float*)d_in[6];
    const float* be1   = (const float*)d_in[7];
    const float* ln_w2 = (const float*)d_in[8];  const float* ln_b2 = (const float*)d_in[9];
    const float* Wb2   = (const float*)d_in[10]; const float* bb2   = (const float*)d_in[11];
    const float* Ws2   = (const float*)d_in[12]; const float* g2    = (const float*)d_in[13];
    const float* be2   = (const float*)d_in[14];
    const float* ln_w3 = (const float*)d_in[15]; const float* ln_b3 = (const float*)d_in[16];
    const float* Wb3   = (const float*)d_in[17]; const float* bb3   = (const float*)d_in[18];
    const float* Ws3   = (const float*)d_in[19]; const float* g3    = (const float*)d_in[20];
    const float* be3   = (const float*)d_in[21];

    const int B = 32;
    char* ws = (char*)d_ws;
    // conv partial region: exactly 33,554,432 B for every layer
    //   L1: 1 x 131072 x 64, L2: 2 x 32768 x 128, L3: 4 x 8192 x 256
    float*  convbuf = (float*)(ws + 0);              // 33,554,432
    float*  poolbuf = (float*)(ws + 33554432);       //  8,388,608
    float*  stats1  = (float*)(ws + 41943040);       //  2048 x3
    float*  stats2  = (float*)(ws + 41945088);
    float*  stats3  = (float*)(ws + 41947136);
    half_t* wt1     = (half_t*)(ws + 41949184);      //   172,032  (64 x 1344)
    half_t* wt2     = (half_t*)(ws + 42121216);      // 1,327,104  (128 x 5184)
    half_t* wt3     = (half_t*)(ws + 43448320);      // 5,308,416  (256 x 10368)
    half_t* pnbuf   = (half_t*)(ws + 48756736);      // 37,748,736 (max 131072x144)
    half_t* spbuf   = (half_t*)(ws + 86505472);      // 37,748,736
    // total: 124,254,208 B

    hipMemsetAsync(stats1, 0, 6144, stream);

    conv_w<144, 64, 1344><<<(64 * 1344 + 255) / 256, 256, 0, stream>>>(Ws1, Wb1, wt1);
    conv_w<576, 128, 5184><<<(128 * 5184 + 255) / 256, 256, 0, stream>>>(Ws2, Wb2, wt2);
    conv_w<1152, 256, 10368><<<(256 * 10368 + 255) / 256, 256, 0, stream>>>(Ws3, Wb3, wt3);

    // ---------------- layer 1: C=16, H=W=64, OUT=64, NB=1, SPLIT=1 ----------
    {
        const int H = 64, W = 64, OUT = 64;
        int npix = B * H * W;                    // 131072
        ln_prep<16, H, W><<<npix / 4, 256, 0, stream>>>(x, ln_w1, ln_b1, pnbuf, spbuf);
        kan_gemm<144, OUT, H * W, 1, 1><<<dim3(npix / 64, 1, 1), 256, 0, stream>>>(
            pnbuf, spbuf, wt1, convbuf);
        bn_stats<1><<<dim3(64, OUT), 256, 0, stream>>>(convbuf, bb1, OUT, H * W, B, stats1);
        long tot = (long)B * OUT * (H / 2) * (W / 2);
        bn_relu_pool<1><<<(tot + 255) / 256, 256, 0, stream>>>(
            convbuf, stats1, bb1, g1, be1, poolbuf, B, OUT, H, W);
    }
    // ---------------- layer 2: C=64, H=W=32, OUT=128, NB=2, SPLIT=2 ---------
    {
        const int H = 32, W = 32, OUT = 128;
        int npix = B * H * W;                    // 32768
        ln_prep<64, H, W><<<npix / 4, 256, 0, stream>>>(poolbuf, ln_w2, ln_b2, pnbuf, spbuf);
        kan_gemm<576, OUT, H * W, 2, 2><<<dim3(npix / 64, 1, 2), 256, 0, stream>>>(
            pnbuf, spbuf, wt2, convbuf);
        bn_stats<2><<<dim3(16, OUT), 256, 0, stream>>>(convbuf, bb2, OUT, H * W, B, stats2);
        long tot = (long)B * OUT * (H / 2) * (W / 2);
        bn_relu_pool<2><<<(tot + 255) / 256, 256, 0, stream>>>(
            convbuf, stats2, bb2, g2, be2, poolbuf, B, OUT, H, W);
    }
    // ---------------- layer 3: C=128, H=W=16, OUT=256, NB=2 (y=2), SPLIT=4 --
    {
        const int H = 16, W = 16, OUT = 256;
        int npix = B * H * W;                    // 8192
        ln_prep<128, H, W><<<npix / 4, 256, 0, stream>>>(poolbuf, ln_w3, ln_b3, pnbuf, spbuf);
        kan_gemm<1152, OUT, H * W, 2, 4><<<dim3(npix / 64, 2, 4), 256, 0, stream>>>(
            pnbuf, spbuf, wt3, convbuf);
        bn_stats<4><<<dim3(8, OUT), 256, 0, stream>>>(convbuf, bb3, OUT, H * W, B, stats3);
        long tot = (long)B * OUT * (H / 2) * (W / 2);  // 524288 == out_size
        bn_relu_pool<4><<<(tot + 255) / 256, 256, 0, stream>>>(
            convbuf, stats3, bb3, g3, be3, (float*)d_out, B, OUT, H, W);
    }
}

// Round 8
// 797.922 us; speedup vs baseline: 1.4925x; 1.4683x over previous
//
#include <hip/hip_runtime.h>

typedef _Float16 half_t;
typedef __attribute__((ext_vector_type(8))) _Float16 half8;
typedef __attribute__((ext_vector_type(4))) float floatx4;

// ---------------------------------------------------------------------------
// Round 8: single-barrier double-buffered K-loop pipeline.
//   prologue: load(it0) -> store buf0 ; issue loads(it0+1)
//   it:       sync -> MFMA(it) from buf[c] -> store(it+1)->buf[1-c]
//             -> issue loads(it+2) -> flip c
// Register re-issue happens only AFTER the consuming store (avoids r7's
// WAR-under-outstanding-load corruption). Atomic-free split-K partials
// summed in BN (r6, verified). XOR-swizzled LDS (conflict-free, r4).
// ---------------------------------------------------------------------------

#define RBF_SCALE 2.1019644f   // 1.75 * sqrt(log2(e))

// ---- patch gather + LayerNorm -> pn' (fp16, pre-scaled), silu (fp16) ----
template<int C, int H, int W>
__global__ __launch_bounds__(256)
void ln_prep(const float* __restrict__ x,
             const float* __restrict__ lnw, const float* __restrict__ lnb,
             half_t* __restrict__ pn, half_t* __restrict__ sp)
{
    const int HW = H * W, IN = C * 9;
    const int NL = (IN + 63) / 64;
    const int wv = threadIdx.x >> 6, lane = threadIdx.x & 63;
    const int pix = blockIdx.x * 4 + wv;
    const int b = pix / HW, hw = pix % HW, h = hw / W, w = hw % W;
    const float* xb = x + (long)b * C * HW;

    float v[NL];
    float s = 0.f, s2 = 0.f;
    #pragma unroll
    for (int t = 0; t < NL; ++t) {
        int i = t * 64 + lane;
        float val = 0.f;
        if (i < IN) {
            int ch = i / 9, r = i - ch * 9;
            int y = h + r / 3 - 1, xx = w + r % 3 - 1;
            if (y >= 0 && y < H && xx >= 0 && xx < W)
                val = xb[ch * HW + y * W + xx];
        }
        v[t] = val; s += val; s2 += val * val;
    }
    #pragma unroll
    for (int off = 32; off > 0; off >>= 1) {
        s  += __shfl_down(s,  off, 64);
        s2 += __shfl_down(s2, off, 64);
    }
    s = __shfl(s, 0, 64); s2 = __shfl(s2, 0, 64);
    float mean = s / IN;
    float istd = rsqrtf(s2 / IN - mean * mean + 1e-5f);

    #pragma unroll
    for (int t = 0; t < NL; ++t) {
        int i = t * 64 + lane;
        if (i < IN) {
            float val = v[t];
            float pnv = (val - mean) * istd * lnw[i] + lnb[i];
            pn[(long)pix * IN + i] = (half_t)(pnv * RBF_SCALE);
            sp[(long)pix * IN + i] = (half_t)(val / (1.f + __expf(-val)));
        }
    }
}

// ---- fp32 weights -> fp16 [OUT][KPAD], j-major k = j*IN + i ----
template<int IN, int OUT, int KPAD>
__global__ __launch_bounds__(256)
void conv_w(const float* __restrict__ Ws, const float* __restrict__ Wb,
            half_t* __restrict__ Wt)
{
    int idx = blockIdx.x * 256 + threadIdx.x;
    if (idx >= OUT * KPAD) return;
    int o = idx / KPAD, k = idx - o * KPAD;
    float v = 0.f;
    if (k < IN * 9) {
        int j = k / IN, i = k - j * IN;
        v = (j < 8) ? Ws[(long)o * IN * 8 + i * 8 + j] : Wb[(long)o * IN + i];
    }
    Wt[idx] = (half_t)v;
}

// ---- fused A-gen + MFMA GEMM, double-buffered single-barrier pipeline ----
template<int IN, int OUT, int HW, int NB, int SPLIT>
__global__ __launch_bounds__(256)
void kan_gemm(const half_t* __restrict__ pn, const half_t* __restrict__ sp,
              const half_t* __restrict__ Wt, float* __restrict__ out)
{
    const int K = IN * 9, KPAD = (K + 63) & ~63, KIT = KPAD / 64;
    const long PSTRIDE = (long)32 * HW * OUT;   // one partial buffer

    __shared__ half_t As[2][64 * 64];
    __shared__ half_t Bs[2][NB * 64 * 64];

    const int tid = threadIdx.x;
    const int row = tid >> 2, q = tid & 3;
    const int pix = blockIdx.x * 64 + row;
    const half_t* pnrow = pn + (long)pix * IN;
    const half_t* sprow = sp + (long)pix * IN;
    const int yoff = blockIdx.y * NB * 64;
    const half_t* wbase = Wt + (long)(yoff + row) * KPAD + q * 16;

    const int wv = tid >> 6, lane = tid & 63;
    const int lr = lane & 15, lq = lane >> 4;
    const int u0 = (2 * q) ^ (row & 7);         // swizzled 16B units
    const int u1 = (2 * q + 1) ^ (row & 7);

    floatx4 acc[NB][4] = {};

    const int it0 = (blockIdx.z * KIT) / SPLIT;
    const int it1 = ((blockIdx.z + 1) * KIT) / SPLIT;

    uint4 breg[2 * NB];
    half8 p0, p1;
    int   jc;

    // ---- prologue: load chunk it0, store into buffer 0 ----
    {
        const int k0 = it0 * 64;
        #pragma unroll
        for (int nb = 0; nb < NB; ++nb) {
            const uint4* src = (const uint4*)(wbase + (long)nb * 64 * KPAD + k0);
            breg[2 * nb]     = src[0];
            breg[2 * nb + 1] = src[1];
        }
        int cs = k0 + q * 16;
        jc = cs / IN;
        if (jc < 8) {
            const half_t* a = pnrow + (cs - jc * IN);
            p0 = *(const half8*)a; p1 = *(const half8*)(a + 8);
        } else if (jc == 8) {
            const half_t* a = sprow + (cs - 8 * IN);
            p0 = *(const half8*)a; p1 = *(const half8*)(a + 8);
        } else {
            p0 = half8{}; p1 = half8{};
        }
        #pragma unroll
        for (int nb = 0; nb < NB; ++nb) {
            int r2 = nb * 64 + row;
            *(uint4*)&Bs[0][r2 * 64 + u0 * 8] = breg[2 * nb];
            *(uint4*)&Bs[0][r2 * 64 + u1 * 8] = breg[2 * nb + 1];
        }
        half8 a0, a1;
        if (jc < 8) {
            float gj = RBF_SCALE * (-2.f + jc * (4.f / 7.f));
            #pragma unroll
            for (int kk = 0; kk < 8; ++kk) {
                float v0 = (float)p0[kk] - gj;
                a0[kk] = (half_t)__builtin_amdgcn_exp2f(-(v0 * v0));
                float v1 = (float)p1[kk] - gj;
                a1[kk] = (half_t)__builtin_amdgcn_exp2f(-(v1 * v1));
            }
        } else {
            a0 = p0; a1 = p1;
        }
        *(half8*)&As[0][row * 64 + u0 * 8] = a0;
        *(half8*)&As[0][row * 64 + u1 * 8] = a1;
    }

    // ---- prologue: issue loads for it0+1 (stores above already consumed) ----
    if (it0 + 1 < it1) {
        const int k0 = (it0 + 1) * 64;
        #pragma unroll
        for (int nb = 0; nb < NB; ++nb) {
            const uint4* src = (const uint4*)(wbase + (long)nb * 64 * KPAD + k0);
            breg[2 * nb]     = src[0];
            breg[2 * nb + 1] = src[1];
        }
        int cs = k0 + q * 16;
        jc = cs / IN;
        if (jc < 8) {
            const half_t* a = pnrow + (cs - jc * IN);
            p0 = *(const half8*)a; p1 = *(const half8*)(a + 8);
        } else if (jc == 8) {
            const half_t* a = sprow + (cs - 8 * IN);
            p0 = *(const half8*)a; p1 = *(const half8*)(a + 8);
        } else {
            p0 = half8{}; p1 = half8{};
        }
    }

    int c = 0;
    for (int it = it0; it < it1; ++it) {
        __syncthreads();   // buf[c] stores (prev iter / prologue) visible

        // ---- MFMA(it) from buf[c] ----
        #pragma unroll
        for (int ks = 0; ks < 2; ++ks) {
            half8 af[4], bf[NB];
            #pragma unroll
            for (int mf = 0; mf < 4; ++mf) {
                int r = mf * 16 + lr;
                af[mf] = *(const half8*)&As[c][r * 64 + (((ks * 4 + lq) ^ (r & 7)) * 8)];
            }
            #pragma unroll
            for (int nb = 0; nb < NB; ++nb) {
                int r = wv * NB * 16 + nb * 16 + lr;
                bf[nb] = *(const half8*)&Bs[c][r * 64 + (((ks * 4 + lq) ^ (r & 7)) * 8)];
            }
            #pragma unroll
            for (int nb = 0; nb < NB; ++nb)
                #pragma unroll
                for (int mf = 0; mf < 4; ++mf)
                    acc[nb][mf] = __builtin_amdgcn_mfma_f32_16x16x32_f16(
                        bf[nb], af[mf], acc[nb][mf], 0, 0, 0);
        }

        if (it + 1 < it1) {
            // ---- store chunk it+1 (regs) into buf[1-c] ----
            #pragma unroll
            for (int nb = 0; nb < NB; ++nb) {
                int r2 = nb * 64 + row;
                *(uint4*)&Bs[1 - c][r2 * 64 + u0 * 8] = breg[2 * nb];
                *(uint4*)&Bs[1 - c][r2 * 64 + u1 * 8] = breg[2 * nb + 1];
            }
            half8 a0, a1;
            if (jc < 8) {
                float gj = RBF_SCALE * (-2.f + jc * (4.f / 7.f));
                #pragma unroll
                for (int kk = 0; kk < 8; ++kk) {
                    float v0 = (float)p0[kk] - gj;
                    a0[kk] = (half_t)__builtin_amdgcn_exp2f(-(v0 * v0));
                    float v1 = (float)p1[kk] - gj;
                    a1[kk] = (half_t)__builtin_amdgcn_exp2f(-(v1 * v1));
                }
            } else {
                a0 = p0; a1 = p1;
            }
            *(half8*)&As[1 - c][row * 64 + u0 * 8] = a0;
            *(half8*)&As[1 - c][row * 64 + u1 * 8] = a1;

            // ---- issue loads for it+2 (regs now free: consumed above) ----
            if (it + 2 < it1) {
                const int k0 = (it + 2) * 64;
                #pragma unroll
                for (int nb = 0; nb < NB; ++nb) {
                    const uint4* src = (const uint4*)(wbase + (long)nb * 64 * KPAD + k0);
                    breg[2 * nb]     = src[0];
                    breg[2 * nb + 1] = src[1];
                }
                int cs = k0 + q * 16;
                jc = cs / IN;
                if (jc < 8) {
                    const half_t* a = pnrow + (cs - jc * IN);
                    p0 = *(const half8*)a; p1 = *(const half8*)(a + 8);
                } else if (jc == 8) {
                    const half_t* a = sprow + (cs - 8 * IN);
                    p0 = *(const half8*)a; p1 = *(const half8*)(a + 8);
                } else {
                    p0 = half8{}; p1 = half8{};
                }
            }
        }
        c ^= 1;
    }

    // ---- epilogue: plain stores into partial[z] ----
    float* pout = out + blockIdx.z * PSTRIDE;
    #pragma unroll
    for (int nb = 0; nb < NB; ++nb)
    #pragma unroll
    for (int mf = 0; mf < 4; ++mf)
    #pragma unroll
    for (int reg = 0; reg < 4; ++reg) {
        int o  = yoff + wv * NB * 16 + nb * 16 + lq * 4 + reg;
        int p2 = blockIdx.x * 64 + mf * 16 + lr;
        int b2 = p2 / HW, hw2 = p2 % HW;
        pout[((long)b2 * OUT + o) * HW + hw2] = acc[nb][mf][reg];
    }
}

// ---- BatchNorm batch-stats over SPLIT partials (conv bias folded in) ----
template<int SPLIT>
__launch_bounds__(256)
__global__ void bn_stats(const float* __restrict__ h, const float* __restrict__ bias,
                         int C, int HW, int B, float* __restrict__ sums)
{
    int c = blockIdx.y;
    float bbc = bias[c];
    int total = B * HW;
    long pstride = (long)total * C;
    float s = 0.f, s2 = 0.f;
    for (int idx = blockIdx.x * 256 + threadIdx.x; idx < total; idx += 256 * gridDim.x) {
        int b = idx / HW, r = idx % HW;
        long off = ((long)b * C + c) * HW + r;
        float v = bbc;
        #pragma unroll
        for (int sp = 0; sp < SPLIT; ++sp) v += h[sp * pstride + off];
        s += v; s2 += v * v;
    }
    for (int off = 32; off > 0; off >>= 1) {
        s  += __shfl_down(s,  off, 64);
        s2 += __shfl_down(s2, off, 64);
    }
    __shared__ float rs[4], rs2[4];
    int lane = threadIdx.x & 63, wid = threadIdx.x >> 6;
    if (lane == 0) { rs[wid] = s; rs2[wid] = s2; }
    __syncthreads();
    if (threadIdx.x == 0) {
        atomicAdd(&sums[c],     rs[0] + rs[1] + rs[2] + rs[3]);
        atomicAdd(&sums[C + c], rs2[0] + rs2[1] + rs2[2] + rs2[3]);
    }
}

template<int SPLIT>
__launch_bounds__(256)
__global__ void bn_relu_pool(const float* __restrict__ h, const float* __restrict__ sums,
                             const float* __restrict__ bias,
                             const float* __restrict__ gamma, const float* __restrict__ beta,
                             float* __restrict__ out, int B, int C, int H, int W)
{
    int Ho = H / 2, Wo = W / 2;
    long total = (long)B * C * Ho * Wo;
    long idx = (long)blockIdx.x * 256 + threadIdx.x;
    if (idx >= total) return;
    int pw = idx % Wo; long t = idx / Wo;
    int ph = t % Ho; t /= Ho;
    int c = t % C; int b = (int)(t / C);

    float M = (float)B * H * W;
    float mean = sums[c] / M;
    float var  = sums[C + c] / M - mean * mean;
    float scale = gamma[c] * rsqrtf(var + 1e-5f);
    float shift = beta[c] - mean * scale + bias[c] * scale;  // fold conv bias

    long pstride = (long)B * C * H * W;
    const float* hp = h + ((long)b * C + c) * H * W;
    float m = 0.f;  // post-relu >= 0
    #pragma unroll
    for (int i = 0; i < 2; ++i)
        #pragma unroll
        for (int j = 0; j < 2; ++j) {
            long off = (2 * ph + i) * W + 2 * pw + j;
            float v = 0.f;
            #pragma unroll
            for (int sp = 0; sp < SPLIT; ++sp) v += hp[sp * pstride + off];
            v = v * scale + shift;
            m = fmaxf(m, v);
        }
    out[idx] = m;
}

extern "C" void kernel_launch(void* const* d_in, const int* in_sizes, int n_in,
                              void* d_out, int out_size, void* d_ws, size_t ws_size,
                              hipStream_t stream) {
    const float* x     = (const float*)d_in[0];
    const float* ln_w1 = (const float*)d_in[1];  const float* ln_b1 = (const float*)d_in[2];
    const float* Wb1   = (const float*)d_in[3];  const float* bb1   = (const float*)d_in[4];
    const float* Ws1   = (const float*)d_in[5];  const float* g1    = (const float*)d_in[6];
    const float* be1   = (const float*)d_in[7];
    const float* ln_w2 = (const float*)d_in[8];  const float* ln_b2 = (const float*)d_in[9];
    const float* Wb2   = (const float*)d_in[10]; const float* bb2   = (const float*)d_in[11];
    const float* Ws2   = (const float*)d_in[12]; const float* g2    = (const float*)d_in[13];
    const float* be2   = (const float*)d_in[14];
    const float* ln_w3 = (const float*)d_in[15]; const float* ln_b3 = (const float*)d_in[16];
    const float* Wb3   = (const float*)d_in[17]; const float* bb3   = (const float*)d_in[18];
    const float* Ws3   = (const float*)d_in[19]; const float* g3    = (const float*)d_in[20];
    const float* be3   = (const float*)d_in[21];

    const int B = 32;
    char* ws = (char*)d_ws;
    // conv partial region: exactly 33,554,432 B for every layer
    //   L1: 1 x 131072 x 64, L2: 2 x 32768 x 128, L3: 4 x 8192 x 256
    float*  convbuf = (float*)(ws + 0);              // 33,554,432
    float*  poolbuf = (float*)(ws + 33554432);       //  8,388,608
    float*  stats1  = (float*)(ws + 41943040);       //  2048 x3
    float*  stats2  = (float*)(ws + 41945088);
    float*  stats3  = (float*)(ws + 41947136);
    half_t* wt1     = (half_t*)(ws + 41949184);      //   172,032  (64 x 1344)
    half_t* wt2     = (half_t*)(ws + 42121216);      // 1,327,104  (128 x 5184)
    half_t* wt3     = (half_t*)(ws + 43448320);      // 5,308,416  (256 x 10368)
    half_t* pnbuf   = (half_t*)(ws + 48756736);      // 37,748,736 (max 131072x144)
    half_t* spbuf   = (half_t*)(ws + 86505472);      // 37,748,736
    // total: 124,254,208 B

    hipMemsetAsync(stats1, 0, 6144, stream);

    conv_w<144, 64, 1344><<<(64 * 1344 + 255) / 256, 256, 0, stream>>>(Ws1, Wb1, wt1);
    conv_w<576, 128, 5184><<<(128 * 5184 + 255) / 256, 256, 0, stream>>>(Ws2, Wb2, wt2);
    conv_w<1152, 256, 10368><<<(256 * 10368 + 255) / 256, 256, 0, stream>>>(Ws3, Wb3, wt3);

    // ---------------- layer 1: C=16, H=W=64, OUT=64, NB=1, SPLIT=1 ----------
    {
        const int H = 64, W = 64, OUT = 64;
        int npix = B * H * W;                    // 131072
        ln_prep<16, H, W><<<npix / 4, 256, 0, stream>>>(x, ln_w1, ln_b1, pnbuf, spbuf);
        kan_gemm<144, OUT, H * W, 1, 1><<<dim3(npix / 64, 1, 1), 256, 0, stream>>>(
            pnbuf, spbuf, wt1, convbuf);
        bn_stats<1><<<dim3(64, OUT), 256, 0, stream>>>(convbuf, bb1, OUT, H * W, B, stats1);
        long tot = (long)B * OUT * (H / 2) * (W / 2);
        bn_relu_pool<1><<<(tot + 255) / 256, 256, 0, stream>>>(
            convbuf, stats1, bb1, g1, be1, poolbuf, B, OUT, H, W);
    }
    // ---------------- layer 2: C=64, H=W=32, OUT=128, NB=2, SPLIT=2 ---------
    {
        const int H = 32, W = 32, OUT = 128;
        int npix = B * H * W;                    // 32768
        ln_prep<64, H, W><<<npix / 4, 256, 0, stream>>>(poolbuf, ln_w2, ln_b2, pnbuf, spbuf);
        kan_gemm<576, OUT, H * W, 2, 2><<<dim3(npix / 64, 1, 2), 256, 0, stream>>>(
            pnbuf, spbuf, wt2, convbuf);
        bn_stats<2><<<dim3(16, OUT), 256, 0, stream>>>(convbuf, bb2, OUT, H * W, B, stats2);
        long tot = (long)B * OUT * (H / 2) * (W / 2);
        bn_relu_pool<2><<<(tot + 255) / 256, 256, 0, stream>>>(
            convbuf, stats2, bb2, g2, be2, poolbuf, B, OUT, H, W);
    }
    // ---------------- layer 3: C=128, H=W=16, OUT=256, NB=2 (y=2), SPLIT=4 --
    {
        const int H = 16, W = 16, OUT = 256;
        int npix = B * H * W;                    // 8192
        ln_prep<128, H, W><<<npix / 4, 256, 0, stream>>>(poolbuf, ln_w3, ln_b3, pnbuf, spbuf);
        kan_gemm<1152, OUT, H * W, 2, 4><<<dim3(npix / 64, 2, 4), 256, 0, stream>>>(
            pnbuf, spbuf, wt3, convbuf);
        bn_stats<4><<<dim3(8, OUT), 256, 0, stream>>>(convbuf, bb3, OUT, H * W, B, stats3);
        long tot = (long)B * OUT * (H / 2) * (W / 2);  // 524288 == out_size
        bn_relu_pool<4><<<(tot + 255) / 256, 256, 0, stream>>>(
            convbuf, stats3, bb3, g3, be3, (float*)d_out, B, OUT, H, W);
    }
}

// Round 9
// 557.817 us; speedup vs baseline: 2.1349x; 1.4304x over previous
//
#include <hip/hip_runtime.h>

typedef _Float16 half_t;
typedef __attribute__((ext_vector_type(8))) _Float16 half8;
typedef __attribute__((ext_vector_type(4))) float floatx4;

// ---------------------------------------------------------------------------
// Round 9: back to the r4 2-barrier K-loop (r5-r8 pipelining attempts all
// regressed: compiler spills prefetch regs / waitcnt hazards). New lever:
// M-tile = 128 pixels per block -> 2x MFMA per barrier, half the weight
// re-reads, half the A-gen per FLOP. acc[NB][8]. Atomic-free split-K
// (partial buffers summed in BN, r6-verified). XOR-swizzled LDS (r4).
// ---------------------------------------------------------------------------

#define RBF_SCALE 2.1019644f   // 1.75 * sqrt(log2(e))

// ---- patch gather + LayerNorm -> pn' (fp16, pre-scaled), silu (fp16) ----
template<int C, int H, int W>
__global__ __launch_bounds__(256)
void ln_prep(const float* __restrict__ x,
             const float* __restrict__ lnw, const float* __restrict__ lnb,
             half_t* __restrict__ pn, half_t* __restrict__ sp)
{
    const int HW = H * W, IN = C * 9;
    const int NL = (IN + 63) / 64;
    const int wv = threadIdx.x >> 6, lane = threadIdx.x & 63;
    const int pix = blockIdx.x * 4 + wv;
    const int b = pix / HW, hw = pix % HW, h = hw / W, w = hw % W;
    const float* xb = x + (long)b * C * HW;

    float v[NL];
    float s = 0.f, s2 = 0.f;
    #pragma unroll
    for (int t = 0; t < NL; ++t) {
        int i = t * 64 + lane;
        float val = 0.f;
        if (i < IN) {
            int ch = i / 9, r = i - ch * 9;
            int y = h + r / 3 - 1, xx = w + r % 3 - 1;
            if (y >= 0 && y < H && xx >= 0 && xx < W)
                val = xb[ch * HW + y * W + xx];
        }
        v[t] = val; s += val; s2 += val * val;
    }
    #pragma unroll
    for (int off = 32; off > 0; off >>= 1) {
        s  += __shfl_down(s,  off, 64);
        s2 += __shfl_down(s2, off, 64);
    }
    s = __shfl(s, 0, 64); s2 = __shfl(s2, 0, 64);
    float mean = s / IN;
    float istd = rsqrtf(s2 / IN - mean * mean + 1e-5f);

    #pragma unroll
    for (int t = 0; t < NL; ++t) {
        int i = t * 64 + lane;
        if (i < IN) {
            float val = v[t];
            float pnv = (val - mean) * istd * lnw[i] + lnb[i];
            pn[(long)pix * IN + i] = (half_t)(pnv * RBF_SCALE);
            sp[(long)pix * IN + i] = (half_t)(val / (1.f + __expf(-val)));
        }
    }
}

// ---- fp32 weights -> fp16 [OUT][KPAD], j-major k = j*IN + i ----
template<int IN, int OUT, int KPAD>
__global__ __launch_bounds__(256)
void conv_w(const float* __restrict__ Ws, const float* __restrict__ Wb,
            half_t* __restrict__ Wt)
{
    int idx = blockIdx.x * 256 + threadIdx.x;
    if (idx >= OUT * KPAD) return;
    int o = idx / KPAD, k = idx - o * KPAD;
    float v = 0.f;
    if (k < IN * 9) {
        int j = k / IN, i = k - j * IN;
        v = (j < 8) ? Ws[(long)o * IN * 8 + i * 8 + j] : Wb[(long)o * IN + i];
    }
    Wt[idx] = (half_t)v;
}

// ---- fused A-gen + MFMA GEMM; block = 128 pixels x NB*64 outputs ----
template<int IN, int OUT, int HW, int NB, int SPLIT>
__global__ __launch_bounds__(256)
void kan_gemm(const half_t* __restrict__ pn, const half_t* __restrict__ sp,
              const half_t* __restrict__ Wt, float* __restrict__ out)
{
    const int K = IN * 9, KPAD = (K + 63) & ~63, KIT = KPAD / 64;
    const long PSTRIDE = (long)32 * HW * OUT;   // one partial buffer

    __shared__ half_t As[128 * 64];   // 128 pixels x 64 k (swizzled)
    __shared__ half_t Bs[NB * 64 * 64];

    const int tid = threadIdx.x;

    // A staging role: 2 threads per pixel row, each covers 32 k (2x16 groups)
    const int arow = tid >> 1, aq = tid & 1;
    const int apix = blockIdx.x * 128 + arow;
    const half_t* pnrow = pn + (long)apix * IN;
    const half_t* sprow = sp + (long)apix * IN;
    const int aswz = arow & 7;

    // B staging role: 4 threads per weight row, each covers 16 k
    const int brow = tid >> 2, bq = tid & 3;
    const int yoff = blockIdx.y * NB * 64;
    const half_t* wbase = Wt + (long)(yoff + brow) * KPAD + bq * 16;
    const int bu0 = (2 * bq) ^ (brow & 7);
    const int bu1 = (2 * bq + 1) ^ (brow & 7);

    // mfma role: wave wv covers outputs (wv*NB..wv*NB+NB-1)*16, all 128 pix
    const int wv = tid >> 6, lane = tid & 63;
    const int lr = lane & 15, lq = lane >> 4;

    floatx4 acc[NB][8] = {};

    const int it0 = (blockIdx.z * KIT) / SPLIT;
    const int it1 = ((blockIdx.z + 1) * KIT) / SPLIT;

    for (int it = it0; it < it1; ++it) {
        const int k0 = it * 64;
        __syncthreads();   // previous MFMA reads done

        // ---- stage B (NB tiles of 64 outputs x 64 k) ----
        #pragma unroll
        for (int nb = 0; nb < NB; ++nb) {
            const uint4* src = (const uint4*)(wbase + (long)nb * 64 * KPAD + k0);
            int r2 = nb * 64 + brow;
            *(uint4*)&Bs[r2 * 64 + bu0 * 8] = src[0];
            *(uint4*)&Bs[r2 * 64 + bu1 * 8] = src[1];
        }

        // ---- stage A: 2 groups of 16 k, uniform j per group (IN%16==0) ----
        #pragma unroll
        for (int g = 0; g < 2; ++g) {
            int cs = k0 + aq * 32 + g * 16;
            int j = cs / IN;
            half8 a0, a1;
            if (j < 8) {
                const half_t* a = pnrow + (cs - j * IN);
                half8 p0 = *(const half8*)a, p1 = *(const half8*)(a + 8);
                float gj = RBF_SCALE * (-2.f + j * (4.f / 7.f));
                #pragma unroll
                for (int kk = 0; kk < 8; ++kk) {
                    float v0 = (float)p0[kk] - gj;
                    a0[kk] = (half_t)__builtin_amdgcn_exp2f(-(v0 * v0));
                    float v1 = (float)p1[kk] - gj;
                    a1[kk] = (half_t)__builtin_amdgcn_exp2f(-(v1 * v1));
                }
            } else if (j == 8) {
                const half_t* a = sprow + (cs - 8 * IN);
                a0 = *(const half8*)a; a1 = *(const half8*)(a + 8);
            } else {
                a0 = half8{}; a1 = half8{};
            }
            int ub = 4 * aq + 2 * g;
            *(half8*)&As[arow * 64 + ((ub)     ^ aswz) * 8] = a0;
            *(half8*)&As[arow * 64 + ((ub + 1) ^ aswz) * 8] = a1;
        }
        __syncthreads();

        // ---- MFMA: 2 k-halves x 8 m-frags x NB n-frags ----
        #pragma unroll
        for (int ks = 0; ks < 2; ++ks) {
            half8 af[8], bf[NB];
            #pragma unroll
            for (int mf = 0; mf < 8; ++mf) {
                int r = mf * 16 + lr;
                af[mf] = *(const half8*)&As[r * 64 + (((ks * 4 + lq) ^ (r & 7)) * 8)];
            }
            #pragma unroll
            for (int nb = 0; nb < NB; ++nb) {
                int r = (wv * NB + nb) * 16 + lr;
                bf[nb] = *(const half8*)&Bs[r * 64 + (((ks * 4 + lq) ^ (r & 7)) * 8)];
            }
            #pragma unroll
            for (int nb = 0; nb < NB; ++nb)
                #pragma unroll
                for (int mf = 0; mf < 8; ++mf)
                    acc[nb][mf] = __builtin_amdgcn_mfma_f32_16x16x32_f16(
                        bf[nb], af[mf], acc[nb][mf], 0, 0, 0);
        }
    }

    // ---- epilogue: plain stores into partial[z] ----
    float* pout = out + blockIdx.z * PSTRIDE;
    #pragma unroll
    for (int nb = 0; nb < NB; ++nb)
    #pragma unroll
    for (int mf = 0; mf < 8; ++mf)
    #pragma unroll
    for (int reg = 0; reg < 4; ++reg) {
        int o  = yoff + (wv * NB + nb) * 16 + lq * 4 + reg;
        int p2 = blockIdx.x * 128 + mf * 16 + lr;
        int b2 = p2 / HW, hw2 = p2 % HW;
        pout[((long)b2 * OUT + o) * HW + hw2] = acc[nb][mf][reg];
    }
}

// ---- BatchNorm batch-stats over SPLIT partials (conv bias folded in) ----
template<int SPLIT>
__launch_bounds__(256)
__global__ void bn_stats(const float* __restrict__ h, const float* __restrict__ bias,
                         int C, int HW, int B, float* __restrict__ sums)
{
    int c = blockIdx.y;
    float bbc = bias[c];
    int total = B * HW;
    long pstride = (long)total * C;
    float s = 0.f, s2 = 0.f;
    for (int idx = blockIdx.x * 256 + threadIdx.x; idx < total; idx += 256 * gridDim.x) {
        int b = idx / HW, r = idx % HW;
        long off = ((long)b * C + c) * HW + r;
        float v = bbc;
        #pragma unroll
        for (int sp = 0; sp < SPLIT; ++sp) v += h[sp * pstride + off];
        s += v; s2 += v * v;
    }
    for (int off = 32; off > 0; off >>= 1) {
        s  += __shfl_down(s,  off, 64);
        s2 += __shfl_down(s2, off, 64);
    }
    __shared__ float rs[4], rs2[4];
    int lane = threadIdx.x & 63, wid = threadIdx.x >> 6;
    if (lane == 0) { rs[wid] = s; rs2[wid] = s2; }
    __syncthreads();
    if (threadIdx.x == 0) {
        atomicAdd(&sums[c],     rs[0] + rs[1] + rs[2] + rs[3]);
        atomicAdd(&sums[C + c], rs2[0] + rs2[1] + rs2[2] + rs2[3]);
    }
}

template<int SPLIT>
__launch_bounds__(256)
__global__ void bn_relu_pool(const float* __restrict__ h, const float* __restrict__ sums,
                             const float* __restrict__ bias,
                             const float* __restrict__ gamma, const float* __restrict__ beta,
                             float* __restrict__ out, int B, int C, int H, int W)
{
    int Ho = H / 2, Wo = W / 2;
    long total = (long)B * C * Ho * Wo;
    long idx = (long)blockIdx.x * 256 + threadIdx.x;
    if (idx >= total) return;
    int pw = idx % Wo; long t = idx / Wo;
    int ph = t % Ho; t /= Ho;
    int c = t % C; int b = (int)(t / C);

    float M = (float)B * H * W;
    float mean = sums[c] / M;
    float var  = sums[C + c] / M - mean * mean;
    float scale = gamma[c] * rsqrtf(var + 1e-5f);
    float shift = beta[c] - mean * scale + bias[c] * scale;  // fold conv bias

    long pstride = (long)B * C * H * W;
    const float* hp = h + ((long)b * C + c) * H * W;
    float m = 0.f;  // post-relu >= 0
    #pragma unroll
    for (int i = 0; i < 2; ++i)
        #pragma unroll
        for (int j = 0; j < 2; ++j) {
            long off = (2 * ph + i) * W + 2 * pw + j;
            float v = 0.f;
            #pragma unroll
            for (int sp = 0; sp < SPLIT; ++sp) v += hp[sp * pstride + off];
            v = v * scale + shift;
            m = fmaxf(m, v);
        }
    out[idx] = m;
}

extern "C" void kernel_launch(void* const* d_in, const int* in_sizes, int n_in,
                              void* d_out, int out_size, void* d_ws, size_t ws_size,
                              hipStream_t stream) {
    const float* x     = (const float*)d_in[0];
    const float* ln_w1 = (const float*)d_in[1];  const float* ln_b1 = (const float*)d_in[2];
    const float* Wb1   = (const float*)d_in[3];  const float* bb1   = (const float*)d_in[4];
    const float* Ws1   = (const float*)d_in[5];  const float* g1    = (const float*)d_in[6];
    const float* be1   = (const float*)d_in[7];
    const float* ln_w2 = (const float*)d_in[8];  const float* ln_b2 = (const float*)d_in[9];
    const float* Wb2   = (const float*)d_in[10]; const float* bb2   = (const float*)d_in[11];
    const float* Ws2   = (const float*)d_in[12]; const float* g2    = (const float*)d_in[13];
    const float* be2   = (const float*)d_in[14];
    const float* ln_w3 = (const float*)d_in[15]; const float* ln_b3 = (const float*)d_in[16];
    const float* Wb3   = (const float*)d_in[17]; const float* bb3   = (const float*)d_in[18];
    const float* Ws3   = (const float*)d_in[19]; const float* g3    = (const float*)d_in[20];
    const float* be3   = (const float*)d_in[21];

    const int B = 32;
    char* ws = (char*)d_ws;
    // conv partial region: exactly 33,554,432 B for every layer
    //   L1: 1 x 131072 x 64, L2: 2 x 32768 x 128, L3: 4 x 8192 x 256
    float*  convbuf = (float*)(ws + 0);              // 33,554,432
    float*  poolbuf = (float*)(ws + 33554432);       //  8,388,608
    float*  stats1  = (float*)(ws + 41943040);       //  2048 x3
    float*  stats2  = (float*)(ws + 41945088);
    float*  stats3  = (float*)(ws + 41947136);
    half_t* wt1     = (half_t*)(ws + 41949184);      //   172,032  (64 x 1344)
    half_t* wt2     = (half_t*)(ws + 42121216);      // 1,327,104  (128 x 5184)
    half_t* wt3     = (half_t*)(ws + 43448320);      // 5,308,416  (256 x 10368)
    half_t* pnbuf   = (half_t*)(ws + 48756736);      // 37,748,736 (max 131072x144)
    half_t* spbuf   = (half_t*)(ws + 86505472);      // 37,748,736
    // total: 124,254,208 B

    hipMemsetAsync(stats1, 0, 6144, stream);

    conv_w<144, 64, 1344><<<(64 * 1344 + 255) / 256, 256, 0, stream>>>(Ws1, Wb1, wt1);
    conv_w<576, 128, 5184><<<(128 * 5184 + 255) / 256, 256, 0, stream>>>(Ws2, Wb2, wt2);
    conv_w<1152, 256, 10368><<<(256 * 10368 + 255) / 256, 256, 0, stream>>>(Ws3, Wb3, wt3);

    // ---------------- layer 1: C=16, H=W=64, OUT=64, NB=1, SPLIT=1 ----------
    {
        const int H = 64, W = 64, OUT = 64;
        int npix = B * H * W;                    // 131072
        ln_prep<16, H, W><<<npix / 4, 256, 0, stream>>>(x, ln_w1, ln_b1, pnbuf, spbuf);
        kan_gemm<144, OUT, H * W, 1, 1><<<dim3(npix / 128, 1, 1), 256, 0, stream>>>(
            pnbuf, spbuf, wt1, convbuf);
        bn_stats<1><<<dim3(64, OUT), 256, 0, stream>>>(convbuf, bb1, OUT, H * W, B, stats1);
        long tot = (long)B * OUT * (H / 2) * (W / 2);
        bn_relu_pool<1><<<(tot + 255) / 256, 256, 0, stream>>>(
            convbuf, stats1, bb1, g1, be1, poolbuf, B, OUT, H, W);
    }
    // ---------------- layer 2: C=64, H=W=32, OUT=128, NB=2, SPLIT=2 ---------
    {
        const int H = 32, W = 32, OUT = 128;
        int npix = B * H * W;                    // 32768
        ln_prep<64, H, W><<<npix / 4, 256, 0, stream>>>(poolbuf, ln_w2, ln_b2, pnbuf, spbuf);
        kan_gemm<576, OUT, H * W, 2, 2><<<dim3(npix / 128, 1, 2), 256, 0, stream>>>(
            pnbuf, spbuf, wt2, convbuf);
        bn_stats<2><<<dim3(16, OUT), 256, 0, stream>>>(convbuf, bb2, OUT, H * W, B, stats2);
        long tot = (long)B * OUT * (H / 2) * (W / 2);
        bn_relu_pool<2><<<(tot + 255) / 256, 256, 0, stream>>>(
            convbuf, stats2, bb2, g2, be2, poolbuf, B, OUT, H, W);
    }
    // ---------------- layer 3: C=128, H=W=16, OUT=256, NB=2 (y=2), SPLIT=4 --
    {
        const int H = 16, W = 16, OUT = 256;
        int npix = B * H * W;                    // 8192
        ln_prep<128, H, W><<<npix / 4, 256, 0, stream>>>(poolbuf, ln_w3, ln_b3, pnbuf, spbuf);
        kan_gemm<1152, OUT, H * W, 2, 4><<<dim3(npix / 128, 2, 4), 256, 0, stream>>>(
            pnbuf, spbuf, wt3, convbuf);
        bn_stats<4><<<dim3(8, OUT), 256, 0, stream>>>(convbuf, bb3, OUT, H * W, B, stats3);
        long tot = (long)B * OUT * (H / 2) * (W / 2);  // 524288 == out_size
        bn_relu_pool<4><<<(tot + 255) / 256, 256, 0, stream>>>(
            convbuf, stats3, bb3, g3, be3, (float*)d_out, B, OUT, H, W);
    }
}